// Round 13
// baseline (436.495 us; speedup 1.0000x reference)
//
#include <hip/hip_runtime.h>
#include <hip/hip_bf16.h>
#include <cstdint>

#define ASPACE(n) __attribute__((address_space(n)))

typedef short bf16x8 __attribute__((ext_vector_type(8)));
typedef float f32x4 __attribute__((ext_vector_type(4)));

__device__ __forceinline__ unsigned short f2bf(float f) {
  uint32_t u = __float_as_uint(f);
  u += 0x7fffu + ((u >> 16) & 1u);
  return (unsigned short)(u >> 16);
}
__device__ __forceinline__ float bf2f(unsigned short h) {
  return __uint_as_float(((uint32_t)h) << 16);
}

// pack 8 fp32 -> bf16x8 via v_cvt_pk_bf16_f32 (RNE)
__device__ __forceinline__ bf16x8 cvt8(float4 a, float4 b) {
  union { uint32_t u[4]; bf16x8 v; } r;
  asm("v_cvt_pk_bf16_f32 %0, %1, %2" : "=v"(r.u[0]) : "v"(a.x), "v"(a.y));
  asm("v_cvt_pk_bf16_f32 %0, %1, %2" : "=v"(r.u[1]) : "v"(a.z), "v"(a.w));
  asm("v_cvt_pk_bf16_f32 %0, %1, %2" : "=v"(r.u[2]) : "v"(b.x), "v"(b.y));
  asm("v_cvt_pk_bf16_f32 %0, %1, %2" : "=v"(r.u[3]) : "v"(b.z), "v"(b.w));
  return r.v;
}

// ---------------- fp32 -> bf16 conversion (weights only) ----------------
__global__ __launch_bounds__(256) void conv_f32_bf16(const float4* __restrict__ src,
                                                     ushort4* __restrict__ dst, int n4) {
  int i = blockIdx.x * blockDim.x + threadIdx.x;
  int stride = gridDim.x * blockDim.x;
  for (; i < n4; i += stride) {
    float4 v = src[i];
    ushort4 o;
    o.x = f2bf(v.x); o.y = f2bf(v.y); o.z = f2bf(v.z); o.w = f2bf(v.w);
    dst[i] = o;
  }
}

__device__ __forceinline__ void gload16(const unsigned short* g, unsigned short* l) {
  __builtin_amdgcn_global_load_lds((const ASPACE(1) void*)g, (ASPACE(3) void*)l, 16, 0, 0);
}
__device__ __forceinline__ void gload16f(const float* g, float* l) {
  __builtin_amdgcn_global_load_lds((const ASPACE(1) void*)g, (ASPACE(3) void*)l, 16, 0, 0);
}

// ---------------- QKV GEMM with fp32 A (reads x directly, no conv pass) ----------------
// C[m,n] = sum_k bf16(A[m,k]) * B[n,k]; BM=128, BN=192, BK=32; r7-proven 2-phase loop.
// A staged as fp32 via gload16 DMA (rows = 8 x 16B chunks, swizzle chunk ^= row&7 both
// sides -> bank-uniform frag reads). Fragments: 2x float4 ds_read + cvt_pk -> bf16x8.
__global__ __launch_bounds__(256, 2) void gemm_qkv_xf32(const float* __restrict__ A,
                                                        const unsigned short* __restrict__ B,
                                                        unsigned short* __restrict__ C,
                                                        int M, int N, int K) {
  __shared__ float Asf[2][128 * 32];            // 32 KiB
  __shared__ unsigned short Bs[2][192 * 32];    // 24 KiB

  const int tid  = threadIdx.x;
  const int lane = tid & 63;
  const int wave = tid >> 6;
  const int wr = wave >> 1;        // 0..1 -> 64-row band
  const int wc = wave & 1;         // 0..1 -> 96-col band

  const int nwg = gridDim.x;       // 6144, %8==0
  const int swz = (blockIdx.x & 7) * (nwg >> 3) + (blockIdx.x >> 3);
  const int ntn = N / 192;
  const int bn0 = (swz % ntn) * 192;
  const int bm0 = (swz / ntn) << 7;

  const float* Abase = A + (size_t)bm0 * K;
  const unsigned short* Bbase = B + (size_t)bn0 * K;

  // A staging: 128 rows x 8 chunks(16B=4 f32) = 1024 chunks; 4 per thread.
  // phys chunk (r,pc) holds global chunk pc^(r&7).
  const float* gA[4];
  float* lA[4];
#pragma unroll
  for (int i = 0; i < 4; ++i) {
    const int c = i * 256 + tid;
    const int r = c >> 3;
    const int gc = (c & 7) ^ (r & 7);
    gA[i] = Abase + (size_t)r * K + gc * 4;
    lA[i] = (float*)Asf + (i * 256 + wave * 64) * 4;
  }
  // B staging: r7-proven (768 chunks, 3/thread, swizzle (row>>1)&3)
  const unsigned short* gB[3];
  unsigned short* lB[3];
#pragma unroll
  for (int i = 0; i < 3; ++i) {
    const int c = i * 256 + tid;
    const int r = c >> 2;
    const int gc = (c & 3) ^ ((r >> 1) & 3);
    gB[i] = Bbase + (size_t)r * K + gc * 8;
    lB[i] = (unsigned short*)Bs + (i * 256 + wave * 64) * 8;
  }
  const int abufoff = 128 * 32;   // floats per A buffer
  const int bbufoff = 192 * 32;   // shorts per B buffer

  const int fr = lane & 15;
  const int hi = lane >> 4;
  // A frag: row, logical chunks 2hi,2hi+1 -> phys p0=(2hi)^(row&7), p1=p0^1
  int afo[4];
#pragma unroll
  for (int m = 0; m < 4; ++m) {
    const int row = wr * 64 + m * 16 + fr;
    afo[m] = row * 32 + (((2 * hi) ^ (row & 7)) * 4);   // float units
  }
  int bfo[6];
#pragma unroll
  for (int n = 0; n < 6; ++n) {
    const int row = wc * 96 + n * 16 + fr;
    bfo[n] = row * 32 + ((hi ^ ((row >> 1) & 3)) * 8);  // short units
  }

  f32x4 acc[4][6];
#pragma unroll
  for (int m = 0; m < 4; ++m)
#pragma unroll
    for (int n = 0; n < 6; ++n) {
      f32x4 z = {0.f, 0.f, 0.f, 0.f};
      acc[m][n] = z;
    }

  const int NT = K >> 5;          // 12

  // prologue: stage tile 0 into buf 0
#pragma unroll
  for (int i = 0; i < 4; ++i) gload16f(gA[i], lA[i]);
#pragma unroll
  for (int i = 0; i < 3; ++i) gload16(gB[i], lB[i]);
  __syncthreads();

  int cur = 0;
  for (int t = 0; t < NT; ++t) {
    if (t + 1 < NT) {             // stage next tile into buf cur^1 (overlaps compute)
      const int nb = cur ^ 1;
      const int k0 = (t + 1) << 5;
#pragma unroll
      for (int i = 0; i < 4; ++i) gload16f(gA[i] + k0, lA[i] + nb * abufoff);
#pragma unroll
      for (int i = 0; i < 3; ++i) gload16(gB[i] + k0, lB[i] + nb * bbufoff);
    }
    {
      const float* Af = (const float*)Asf + cur * abufoff;
      const unsigned short* Bb = (const unsigned short*)Bs + cur * bbufoff;
      bf16x8 af[4], bfv[6];
#pragma unroll
      for (int m = 0; m < 4; ++m) {
        float4 lo = *(const float4*)(Af + afo[m]);
        float4 hi4 = *(const float4*)(Af + (afo[m] ^ 4));
        af[m] = cvt8(lo, hi4);
      }
#pragma unroll
      for (int n = 0; n < 6; ++n) bfv[n] = *(const bf16x8*)(Bb + bfo[n]);
#pragma unroll
      for (int m = 0; m < 4; ++m)
#pragma unroll
        for (int n = 0; n < 6; ++n)
          acc[m][n] = __builtin_amdgcn_mfma_f32_16x16x32_bf16(af[m], bfv[n], acc[m][n], 0, 0, 0);
    }
    __syncthreads();
    cur ^= 1;
  }

  // epilogue: C/D layout col = lane&15, row = (lane>>4)*4 + reg
  const int rq = hi * 4;
#pragma unroll
  for (int m = 0; m < 4; ++m) {
#pragma unroll
    for (int n = 0; n < 6; ++n) {
      const int col = bn0 + wc * 96 + n * 16 + fr;
#pragma unroll
      for (int r = 0; r < 4; ++r) {
        const int row = bm0 + wr * 64 + m * 16 + rq + r;
        C[(size_t)row * N + col] = f2bf(acc[m][n][r]);
      }
    }
  }
}

// ---------------- proj GEMM (r7-proven kernel, verbatim; bf16 A) ----------------
template <int OUT_MODE>
__global__ __launch_bounds__(256, 3) void gemm_bt(const unsigned short* __restrict__ A,
                                                  const unsigned short* __restrict__ B,
                                                  void* __restrict__ Cout,
                                                  const float* __restrict__ bias,
                                                  int M, int N, int K) {
  __shared__ unsigned short As[2][128 * 32];
  __shared__ unsigned short Bs[2][192 * 32];

  const int tid  = threadIdx.x;
  const int lane = tid & 63;
  const int wave = tid >> 6;
  const int wr = wave >> 1;
  const int wc = wave & 1;

  const int nwg = gridDim.x;
  const int swz = (blockIdx.x & 7) * (nwg >> 3) + (blockIdx.x >> 3);
  const int ntn = N / 192;
  const int bn0 = (swz % ntn) * 192;
  const int bm0 = (swz / ntn) << 7;

  const unsigned short* Abase = A + (size_t)bm0 * K;
  const unsigned short* Bbase = B + (size_t)bn0 * K;

  const unsigned short* gA[2];
  const unsigned short* gB[3];
  unsigned short* lA[2];
  unsigned short* lB[3];
#pragma unroll
  for (int i = 0; i < 2; ++i) {
    const int c = i * 256 + tid;
    const int r = c >> 2;
    const int gc = (c & 3) ^ ((r >> 1) & 3);
    gA[i] = Abase + (size_t)r * K + gc * 8;
    lA[i] = (unsigned short*)As + (i * 256 + wave * 64) * 8;
  }
#pragma unroll
  for (int i = 0; i < 3; ++i) {
    const int c = i * 256 + tid;
    const int r = c >> 2;
    const int gc = (c & 3) ^ ((r >> 1) & 3);
    gB[i] = Bbase + (size_t)r * K + gc * 8;
    lB[i] = (unsigned short*)Bs + (i * 256 + wave * 64) * 8;
  }
  const int abufoff = 128 * 32;
  const int bbufoff = 192 * 32;

  const int fr = lane & 15;
  const int hi = lane >> 4;
  int afo[4], bfo[6];
#pragma unroll
  for (int m = 0; m < 4; ++m) {
    const int row = wr * 64 + m * 16 + fr;
    afo[m] = row * 32 + ((hi ^ ((row >> 1) & 3)) * 8);
  }
#pragma unroll
  for (int n = 0; n < 6; ++n) {
    const int row = wc * 96 + n * 16 + fr;
    bfo[n] = row * 32 + ((hi ^ ((row >> 1) & 3)) * 8);
  }

  f32x4 acc[4][6];
#pragma unroll
  for (int m = 0; m < 4; ++m)
#pragma unroll
    for (int n = 0; n < 6; ++n) {
      f32x4 z = {0.f, 0.f, 0.f, 0.f};
      acc[m][n] = z;
    }

  const int NT = K >> 5;

#pragma unroll
  for (int i = 0; i < 2; ++i) gload16(gA[i], lA[i]);
#pragma unroll
  for (int i = 0; i < 3; ++i) gload16(gB[i], lB[i]);
  __syncthreads();

  int cur = 0;
  for (int t = 0; t < NT; ++t) {
    if (t + 1 < NT) {
      const int nb = cur ^ 1;
      const int k0 = (t + 1) << 5;
#pragma unroll
      for (int i = 0; i < 2; ++i) gload16(gA[i] + k0, lA[i] + nb * abufoff);
#pragma unroll
      for (int i = 0; i < 3; ++i) gload16(gB[i] + k0, lB[i] + nb * bbufoff);
    }
    {
      const unsigned short* Ab = (const unsigned short*)As + cur * abufoff;
      const unsigned short* Bb = (const unsigned short*)Bs + cur * bbufoff;
      bf16x8 af[4], bfv[6];
#pragma unroll
      for (int m = 0; m < 4; ++m) af[m] = *(const bf16x8*)(Ab + afo[m]);
#pragma unroll
      for (int n = 0; n < 6; ++n) bfv[n] = *(const bf16x8*)(Bb + bfo[n]);
#pragma unroll
      for (int m = 0; m < 4; ++m)
#pragma unroll
        for (int n = 0; n < 6; ++n)
          acc[m][n] = __builtin_amdgcn_mfma_f32_16x16x32_bf16(af[m], bfv[n], acc[m][n], 0, 0, 0);
    }
    __syncthreads();
    cur ^= 1;
  }

  const int rq = hi * 4;
  if (OUT_MODE == 1) {
    float* C = (float*)Cout;
#pragma unroll
    for (int m = 0; m < 4; ++m) {
#pragma unroll
      for (int n = 0; n < 6; ++n) {
        const int col = bn0 + wc * 96 + n * 16 + fr;
        const float bv = bias[col];
#pragma unroll
        for (int r = 0; r < 4; ++r) {
          const int row = bm0 + wr * 64 + m * 16 + rq + r;
          C[(size_t)row * N + col] = acc[m][n][r] + bv;
        }
      }
    }
  } else {
    unsigned short* C = (unsigned short*)Cout;
#pragma unroll
    for (int m = 0; m < 4; ++m) {
#pragma unroll
      for (int n = 0; n < 6; ++n) {
        const int col = bn0 + wc * 96 + n * 16 + fr;
#pragma unroll
        for (int r = 0; r < 4; ++r) {
          const int row = bm0 + wr * 64 + m * 16 + rq + r;
          C[(size_t)row * N + col] = f2bf(acc[m][n][r]);
        }
      }
    }
  }
}

// ---------------- windowed attention (r2/r7-proven, verbatim) ----------------
#define PADV 24
#define PADP 24
__global__ __launch_bounds__(256) void win_attn(const unsigned short* __restrict__ qkv,
                                                unsigned short* __restrict__ aout) {
  __shared__ unsigned short lds[4][48 * PADV + 16 * PADP];
  const int tid = threadIdx.x;
  const int wave = tid >> 6, lane = tid & 63;
  const int wg = blockIdx.x * 4 + wave;     // ((b*1024 + w)*8 + h)
  const int h = wg & 7;
  const int bw = wg >> 3;
  const int w = bw & 1023, b = bw >> 10;
  const int wy = w >> 5, wx = w & 31;

  unsigned short* Vt = lds[wave];
  unsigned short* P  = lds[wave] + 48 * PADV;

  const int lg = lane >> 4;
  const int lr = lane & 15;

  const int n_lr = (wy * 4 + (lr >> 2)) * 128 + wx * 4 + (lr & 3);
  const size_t rowbase = ((size_t)(b * 16384 + n_lr)) * 1152 + h * 48;

  bf16x8 aq0, bk0;
  bf16x8 aq1 = {0, 0, 0, 0, 0, 0, 0, 0};
  bf16x8 bk1 = {0, 0, 0, 0, 0, 0, 0, 0};
  aq0 = *(const bf16x8*)(qkv + rowbase + lg * 8);
  bk0 = *(const bf16x8*)(qkv + rowbase + 384 + lg * 8);
  if (lg < 2) {
    aq1 = *(const bf16x8*)(qkv + rowbase + 32 + lg * 8);
    bk1 = *(const bf16x8*)(qkv + rowbase + 384 + 32 + lg * 8);
  }

  {
    bf16x8 v = *(const bf16x8*)(qkv + rowbase + 768 + lg * 8);
#pragma unroll
    for (int i = 0; i < 8; ++i) Vt[(lg * 8 + i) * PADV + lr] = (unsigned short)v[i];
    if (lane < 32) {
      bf16x8 v2 = *(const bf16x8*)(qkv + rowbase + 768 + 32 + lg * 8);
#pragma unroll
      for (int i = 0; i < 8; ++i) Vt[((4 + lg) * 8 + i) * PADV + lr] = (unsigned short)v2[i];
    }
  }

  f32x4 s = {0.f, 0.f, 0.f, 0.f};
  s = __builtin_amdgcn_mfma_f32_16x16x32_bf16(aq0, bk0, s, 0, 0, 0);
  s = __builtin_amdgcn_mfma_f32_16x16x32_bf16(aq1, bk1, s, 0, 0, 0);

  const float scale = 0.14433756729740643f;  // 1/sqrt(48)
  float p[4];
#pragma unroll
  for (int r = 0; r < 4; ++r) {
    float x = s[r] * scale;
    float m = x;
    m = fmaxf(m, __shfl_xor(m, 1));
    m = fmaxf(m, __shfl_xor(m, 2));
    m = fmaxf(m, __shfl_xor(m, 4));
    m = fmaxf(m, __shfl_xor(m, 8));
    float e = __expf(x - m);
    float t = e;
    t += __shfl_xor(t, 1);
    t += __shfl_xor(t, 2);
    t += __shfl_xor(t, 4);
    t += __shfl_xor(t, 8);
    p[r] = e / t;
  }
#pragma unroll
  for (int r = 0; r < 4; ++r) P[(lg * 4 + r) * PADP + lr] = f2bf(p[r]);

  __syncthreads();

  bf16x8 ap = {0, 0, 0, 0, 0, 0, 0, 0};
  if (lg < 2) ap = *(const bf16x8*)(P + lr * PADP + lg * 8);

  f32x4 o[3];
#pragma unroll
  for (int c = 0; c < 3; ++c) {
    bf16x8 bv = {0, 0, 0, 0, 0, 0, 0, 0};
    if (lg < 2) bv = *(const bf16x8*)(Vt + (c * 16 + lr) * PADV + lg * 8);
    f32x4 z = {0.f, 0.f, 0.f, 0.f};
    o[c] = __builtin_amdgcn_mfma_f32_16x16x32_bf16(ap, bv, z, 0, 0, 0);
  }

#pragma unroll
  for (int r = 0; r < 4; ++r) {
    const int qi = lg * 4 + r;
    const int nq = (wy * 4 + (qi >> 2)) * 128 + wx * 4 + (qi & 3);
    const size_t obase = ((size_t)(b * 16384 + nq)) * 384 + h * 48;
#pragma unroll
    for (int c = 0; c < 3; ++c)
      aout[obase + c * 16 + lr] = f2bf(o[c][r]);
  }
}

// ---------------- launch ----------------
extern "C" void kernel_launch(void* const* d_in, const int* in_sizes, int n_in,
                              void* d_out, int out_size, void* d_ws, size_t ws_size,
                              hipStream_t stream) {
  const float* x      = (const float*)d_in[0];
  const float* W_qkv  = (const float*)d_in[1];
  const float* W_proj = (const float*)d_in[2];
  const float* b_proj = (const float*)d_in[3];
  float* out = (float*)d_out;

  const int Bb = 8, Nn = 16384, Cc = 384;
  const int M = Bb * Nn;       // 131072
  const int threeC = 3 * Cc;   // 1152

  char* ws = (char*)d_ws;
  unsigned short* qkv_bf   = (unsigned short*)ws;                                  // M*1152 bf16
  unsigned short* xa_bf    = (unsigned short*)(ws + (size_t)M * threeC * 2);       // M*384 bf16 (attn out)
  unsigned short* wqkv_bf  = (unsigned short*)(ws + (size_t)M * threeC * 2 + (size_t)M * Cc * 2);
  unsigned short* wproj_bf = wqkv_bf + threeC * Cc;

  // weight conversions only (tiny)
  conv_f32_bf16<<<432, 256, 0, stream>>>((const float4*)W_qkv, (ushort4*)wqkv_bf,
                                         threeC * Cc / 4);
  conv_f32_bf16<<<144, 256, 0, stream>>>((const float4*)W_proj, (ushort4*)wproj_bf,
                                         Cc * Cc / 4);

  // qkv = bf16(x) @ W_qkv^T, reading fp32 x directly: grid = 1024 x 6 = 6144 (%8==0)
  gemm_qkv_xf32<<<(M / 128) * (threeC / 192), 256, 0, stream>>>(x, wqkv_bf, qkv_bf,
                                                                M, threeC, Cc);

  win_attn<<<Bb * 8 * 1024 / 4, 256, 0, stream>>>(qkv_bf, xa_bf);

  // out = attn @ W_proj^T + b (fp32): grid = 1024 x 2 = 2048 (%8==0)
  gemm_bt<1><<<(M / 128) * (Cc / 192), 256, 0, stream>>>(xa_bf, wproj_bf, out, b_proj,
                                                         M, Cc, Cc);
}

// Round 14
// 421.866 us; speedup vs baseline: 1.0347x; 1.0347x over previous
//
#include <hip/hip_runtime.h>
#include <hip/hip_bf16.h>
#include <cstdint>

#define ASPACE(n) __attribute__((address_space(n)))

typedef short bf16x8 __attribute__((ext_vector_type(8)));
typedef float f32x4 __attribute__((ext_vector_type(4)));

__device__ __forceinline__ unsigned short f2bf(float f) {
  uint32_t u = __float_as_uint(f);
  u += 0x7fffu + ((u >> 16) & 1u);
  return (unsigned short)(u >> 16);
}
__device__ __forceinline__ float bf2f(unsigned short h) {
  return __uint_as_float(((uint32_t)h) << 16);
}

// ---------------- fp32 -> bf16 conversion ----------------
__global__ __launch_bounds__(256) void conv_f32_bf16(const float4* __restrict__ src,
                                                     ushort4* __restrict__ dst, int n4) {
  int i = blockIdx.x * blockDim.x + threadIdx.x;
  int stride = gridDim.x * blockDim.x;
  for (; i < n4; i += stride) {
    float4 v = src[i];
    ushort4 o;
    o.x = f2bf(v.x); o.y = f2bf(v.y); o.z = f2bf(v.z); o.w = f2bf(v.w);
    dst[i] = o;
  }
}

__device__ __forceinline__ void gload16(const unsigned short* g, unsigned short* l) {
  __builtin_amdgcn_global_load_lds((const ASPACE(1) void*)g, (ASPACE(3) void*)l, 16, 0, 0);
}

// ---------------- bf16 GEMM (B^T input), r7-proven structure ----------------
// BM=128, BN=192, BK=32; 4 waves (2x2, per-wave 64x96); dbuf LDS 40 KiB, 3 blocks/CU.
// OUT_MODE 0: bf16 out HEAD-MAJOR qkv planes [(col/48)][row][48] (for win_attn reads).
// OUT_MODE 1: fp32 out + bias, row-major [M][N].
template <int OUT_MODE>
__global__ __launch_bounds__(256, 3) void gemm_bt(const unsigned short* __restrict__ A,
                                                  const unsigned short* __restrict__ B,
                                                  void* __restrict__ Cout,
                                                  const float* __restrict__ bias,
                                                  int M, int N, int K) {
  __shared__ unsigned short As[2][128 * 32];
  __shared__ unsigned short Bs[2][192 * 32];

  const int tid  = threadIdx.x;
  const int lane = tid & 63;
  const int wave = tid >> 6;
  const int wr = wave >> 1;
  const int wc = wave & 1;

  const int nwg = gridDim.x;
  const int swz = (blockIdx.x & 7) * (nwg >> 3) + (blockIdx.x >> 3);
  const int ntn = N / 192;
  const int bn0 = (swz % ntn) * 192;
  const int bm0 = (swz / ntn) << 7;

  const unsigned short* Abase = A + (size_t)bm0 * K;
  const unsigned short* Bbase = B + (size_t)bn0 * K;

  const unsigned short* gA[2];
  const unsigned short* gB[3];
  unsigned short* lA[2];
  unsigned short* lB[3];
#pragma unroll
  for (int i = 0; i < 2; ++i) {
    const int c = i * 256 + tid;
    const int r = c >> 2;
    const int gc = (c & 3) ^ ((r >> 1) & 3);
    gA[i] = Abase + (size_t)r * K + gc * 8;
    lA[i] = (unsigned short*)As + (i * 256 + wave * 64) * 8;
  }
#pragma unroll
  for (int i = 0; i < 3; ++i) {
    const int c = i * 256 + tid;
    const int r = c >> 2;
    const int gc = (c & 3) ^ ((r >> 1) & 3);
    gB[i] = Bbase + (size_t)r * K + gc * 8;
    lB[i] = (unsigned short*)Bs + (i * 256 + wave * 64) * 8;
  }
  const int abufoff = 128 * 32;
  const int bbufoff = 192 * 32;

  const int fr = lane & 15;
  const int hi = lane >> 4;
  int afo[4], bfo[6];
#pragma unroll
  for (int m = 0; m < 4; ++m) {
    const int row = wr * 64 + m * 16 + fr;
    afo[m] = row * 32 + ((hi ^ ((row >> 1) & 3)) * 8);
  }
#pragma unroll
  for (int n = 0; n < 6; ++n) {
    const int row = wc * 96 + n * 16 + fr;
    bfo[n] = row * 32 + ((hi ^ ((row >> 1) & 3)) * 8);
  }

  f32x4 acc[4][6];
#pragma unroll
  for (int m = 0; m < 4; ++m)
#pragma unroll
    for (int n = 0; n < 6; ++n) {
      f32x4 z = {0.f, 0.f, 0.f, 0.f};
      acc[m][n] = z;
    }

  const int NT = K >> 5;

#pragma unroll
  for (int i = 0; i < 2; ++i) gload16(gA[i], lA[i]);
#pragma unroll
  for (int i = 0; i < 3; ++i) gload16(gB[i], lB[i]);
  __syncthreads();

  int cur = 0;
  for (int t = 0; t < NT; ++t) {
    if (t + 1 < NT) {
      const int nb = cur ^ 1;
      const int k0 = (t + 1) << 5;
#pragma unroll
      for (int i = 0; i < 2; ++i) gload16(gA[i] + k0, lA[i] + nb * abufoff);
#pragma unroll
      for (int i = 0; i < 3; ++i) gload16(gB[i] + k0, lB[i] + nb * bbufoff);
    }
    {
      const unsigned short* Ab = (const unsigned short*)As + cur * abufoff;
      const unsigned short* Bb = (const unsigned short*)Bs + cur * bbufoff;
      bf16x8 af[4], bfv[6];
#pragma unroll
      for (int m = 0; m < 4; ++m) af[m] = *(const bf16x8*)(Ab + afo[m]);
#pragma unroll
      for (int n = 0; n < 6; ++n) bfv[n] = *(const bf16x8*)(Bb + bfo[n]);
#pragma unroll
      for (int m = 0; m < 4; ++m)
#pragma unroll
        for (int n = 0; n < 6; ++n)
          acc[m][n] = __builtin_amdgcn_mfma_f32_16x16x32_bf16(af[m], bfv[n], acc[m][n], 0, 0, 0);
    }
    __syncthreads();
    cur ^= 1;
  }

  // epilogue: C/D layout col = lane&15, row = (lane>>4)*4 + reg   [guide-verified m89/m91]
  const int rq = hi * 4;
  if (OUT_MODE == 1) {
    float* C = (float*)Cout;
#pragma unroll
    for (int m = 0; m < 4; ++m) {
#pragma unroll
      for (int n = 0; n < 6; ++n) {
        const int col = bn0 + wc * 96 + n * 16 + fr;
        const float bv = bias[col];
#pragma unroll
        for (int r = 0; r < 4; ++r) {
          const int row = bm0 + wr * 64 + m * 16 + rq + r;
          C[(size_t)row * N + col] = acc[m][n][r] + bv;
        }
      }
    }
  } else {
    // head-major planes: plane = col/48 (= p*8+h), d = col%48; addr = (plane*M + row)*48 + d
    // 16-lane span stays in one plane: (bn0 + wc*96 + n*16) % 48 in {0,16,32}.
    unsigned short* C = (unsigned short*)Cout;
#pragma unroll
    for (int m = 0; m < 4; ++m) {
#pragma unroll
      for (int n = 0; n < 6; ++n) {
        const int col = bn0 + wc * 96 + n * 16 + fr;
        const int pl = col / 48;
        const int d  = col - pl * 48;
        unsigned short* base = C + ((size_t)pl * M + bm0 + wr * 64 + m * 16 + rq) * 48 + d;
#pragma unroll
        for (int r = 0; r < 4; ++r)
          base[(size_t)r * 48] = f2bf(acc[m][n][r]);
      }
    }
  }
}

// ---------------- windowed attention (head-major qkv input) ----------------
// qkv planes: q at plane h, k at plane 8+h, v at plane 16+h; plane = [M][48] bf16.
// Window-row cluster reads are 4x 192B contiguous runs (4 consecutive tokens x 48B).
#define PADV 24
#define PADP 24
#define MTOK 131072
__global__ __launch_bounds__(256) void win_attn(const unsigned short* __restrict__ qkv,
                                                unsigned short* __restrict__ aout) {
  __shared__ unsigned short lds[4][48 * PADV + 16 * PADP];
  const int tid = threadIdx.x;
  const int wave = tid >> 6, lane = tid & 63;
  const int wg = blockIdx.x * 4 + wave;     // ((b*1024 + w)*8 + h)
  const int h = wg & 7;
  const int bw = wg >> 3;
  const int w = bw & 1023, b = bw >> 10;
  const int wy = w >> 5, wx = w & 31;

  unsigned short* Vt = lds[wave];
  unsigned short* P  = lds[wave] + 48 * PADV;

  const int lg = lane >> 4;
  const int lr = lane & 15;

  const int gtok = b * 16384 + (wy * 4 + (lr >> 2)) * 128 + wx * 4 + (lr & 3);
  const size_t qb = ((size_t)h * MTOK + gtok) * 48;
  const size_t kb = ((size_t)(8 + h) * MTOK + gtok) * 48;
  const size_t vb = ((size_t)(16 + h) * MTOK + gtok) * 48;

  bf16x8 aq0, bk0;
  bf16x8 aq1 = {0, 0, 0, 0, 0, 0, 0, 0};
  bf16x8 bk1 = {0, 0, 0, 0, 0, 0, 0, 0};
  aq0 = *(const bf16x8*)(qkv + qb + lg * 8);
  bk0 = *(const bf16x8*)(qkv + kb + lg * 8);
  if (lg < 2) {
    aq1 = *(const bf16x8*)(qkv + qb + 32 + lg * 8);
    bk1 = *(const bf16x8*)(qkv + kb + 32 + lg * 8);
  }

  {
    bf16x8 v = *(const bf16x8*)(qkv + vb + lg * 8);
#pragma unroll
    for (int i = 0; i < 8; ++i) Vt[(lg * 8 + i) * PADV + lr] = (unsigned short)v[i];
    if (lane < 32) {
      bf16x8 v2 = *(const bf16x8*)(qkv + vb + 32 + lg * 8);
#pragma unroll
      for (int i = 0; i < 8; ++i) Vt[((4 + lg) * 8 + i) * PADV + lr] = (unsigned short)v2[i];
    }
  }

  f32x4 s = {0.f, 0.f, 0.f, 0.f};
  s = __builtin_amdgcn_mfma_f32_16x16x32_bf16(aq0, bk0, s, 0, 0, 0);
  s = __builtin_amdgcn_mfma_f32_16x16x32_bf16(aq1, bk1, s, 0, 0, 0);

  const float scale = 0.14433756729740643f;  // 1/sqrt(48)
  float p[4];
#pragma unroll
  for (int r = 0; r < 4; ++r) {
    float x = s[r] * scale;
    float m = x;
    m = fmaxf(m, __shfl_xor(m, 1));
    m = fmaxf(m, __shfl_xor(m, 2));
    m = fmaxf(m, __shfl_xor(m, 4));
    m = fmaxf(m, __shfl_xor(m, 8));
    float e = __expf(x - m);
    float t = e;
    t += __shfl_xor(t, 1);
    t += __shfl_xor(t, 2);
    t += __shfl_xor(t, 4);
    t += __shfl_xor(t, 8);
    p[r] = e / t;
  }
#pragma unroll
  for (int r = 0; r < 4; ++r) P[(lg * 4 + r) * PADP + lr] = f2bf(p[r]);

  __syncthreads();

  bf16x8 ap = {0, 0, 0, 0, 0, 0, 0, 0};
  if (lg < 2) ap = *(const bf16x8*)(P + lr * PADP + lg * 8);

  f32x4 o[3];
#pragma unroll
  for (int c = 0; c < 3; ++c) {
    bf16x8 bv = {0, 0, 0, 0, 0, 0, 0, 0};
    if (lg < 2) bv = *(const bf16x8*)(Vt + (c * 16 + lr) * PADV + lg * 8);
    f32x4 z = {0.f, 0.f, 0.f, 0.f};
    o[c] = __builtin_amdgcn_mfma_f32_16x16x32_bf16(ap, bv, z, 0, 0, 0);
  }

#pragma unroll
  for (int r = 0; r < 4; ++r) {
    const int qi = lg * 4 + r;
    const int nq = (wy * 4 + (qi >> 2)) * 128 + wx * 4 + (qi & 3);
    const size_t obase = ((size_t)(b * 16384 + nq)) * 384 + h * 48;
#pragma unroll
    for (int c = 0; c < 3; ++c)
      aout[obase + c * 16 + lr] = f2bf(o[c][r]);
  }
}

// ---------------- launch ----------------
extern "C" void kernel_launch(void* const* d_in, const int* in_sizes, int n_in,
                              void* d_out, int out_size, void* d_ws, size_t ws_size,
                              hipStream_t stream) {
  const float* x      = (const float*)d_in[0];
  const float* W_qkv  = (const float*)d_in[1];
  const float* W_proj = (const float*)d_in[2];
  const float* b_proj = (const float*)d_in[3];
  float* out = (float*)d_out;

  const int Bb = 8, Nn = 16384, Cc = 384;
  const int M = Bb * Nn;       // 131072
  const int threeC = 3 * Cc;   // 1152

  char* ws = (char*)d_ws;
  unsigned short* qkv_bf   = (unsigned short*)ws;                                  // 24 planes [M][48]
  unsigned short* xa_bf    = (unsigned short*)(ws + (size_t)M * threeC * 2);       // M*384 bf16
  unsigned short* wqkv_bf  = (unsigned short*)(ws + (size_t)M * threeC * 2 + (size_t)M * Cc * 2);
  unsigned short* wproj_bf = wqkv_bf + threeC * Cc;

  conv_f32_bf16<<<2048, 256, 0, stream>>>((const float4*)x, (ushort4*)xa_bf, M * Cc / 4);
  conv_f32_bf16<<<432, 256, 0, stream>>>((const float4*)W_qkv, (ushort4*)wqkv_bf, threeC * Cc / 4);
  conv_f32_bf16<<<144, 256, 0, stream>>>((const float4*)W_proj, (ushort4*)wproj_bf, Cc * Cc / 4);

  // qkv = x @ W_qkv^T (bf16, head-major planes): grid = 1024 x 6 = 6144 (%8==0)
  gemm_bt<0><<<(M / 128) * (threeC / 192), 256, 0, stream>>>(xa_bf, wqkv_bf, qkv_bf, nullptr,
                                                             M, threeC, Cc);

  win_attn<<<Bb * 8 * 1024 / 4, 256, 0, stream>>>(qkv_bf, xa_bf);

  // out = attn @ W_proj^T + b (fp32): grid = 1024 x 2 = 2048 (%8==0)
  gemm_bt<1><<<(M / 128) * (Cc / 192), 256, 0, stream>>>(xa_bf, wproj_bf, out, b_proj,
                                                         M, Cc, Cc);
}

// Round 15
// 407.156 us; speedup vs baseline: 1.0721x; 1.0361x over previous
//
#include <hip/hip_runtime.h>
#include <hip/hip_bf16.h>
#include <cstdint>

#define ASPACE(n) __attribute__((address_space(n)))

typedef short bf16x8 __attribute__((ext_vector_type(8)));
typedef float f32x4 __attribute__((ext_vector_type(4)));

__device__ __forceinline__ unsigned short f2bf(float f) {
  uint32_t u = __float_as_uint(f);
  u += 0x7fffu + ((u >> 16) & 1u);
  return (unsigned short)(u >> 16);
}
__device__ __forceinline__ float bf2f(unsigned short h) {
  return __uint_as_float(((uint32_t)h) << 16);
}

// ---------------- fp32 -> bf16 conversion ----------------
__global__ __launch_bounds__(256) void conv_f32_bf16(const float4* __restrict__ src,
                                                     ushort4* __restrict__ dst, int n4) {
  int i = blockIdx.x * blockDim.x + threadIdx.x;
  int stride = gridDim.x * blockDim.x;
  for (; i < n4; i += stride) {
    float4 v = src[i];
    ushort4 o;
    o.x = f2bf(v.x); o.y = f2bf(v.y); o.z = f2bf(v.z); o.w = f2bf(v.w);
    dst[i] = o;
  }
}

__device__ __forceinline__ void gload16(const unsigned short* g, unsigned short* l) {
  __builtin_amdgcn_global_load_lds((const ASPACE(1) void*)g, (ASPACE(3) void*)l, 16, 0, 0);
}

// ---------------- QKV GEMM (r7/r14-proven): bf16 out, HEAD-MAJOR planes ----------------
__global__ __launch_bounds__(256, 3) void gemm_qkv(const unsigned short* __restrict__ A,
                                                   const unsigned short* __restrict__ B,
                                                   unsigned short* __restrict__ C,
                                                   int M, int N, int K) {
  __shared__ unsigned short As[2][128 * 32];
  __shared__ unsigned short Bs[2][192 * 32];

  const int tid  = threadIdx.x;
  const int lane = tid & 63;
  const int wave = tid >> 6;
  const int wr = wave >> 1;
  const int wc = wave & 1;

  const int nwg = gridDim.x;
  const int swz = (blockIdx.x & 7) * (nwg >> 3) + (blockIdx.x >> 3);
  const int ntn = N / 192;
  const int bn0 = (swz % ntn) * 192;
  const int bm0 = (swz / ntn) << 7;

  const unsigned short* Abase = A + (size_t)bm0 * K;
  const unsigned short* Bbase = B + (size_t)bn0 * K;

  const unsigned short* gA[2];
  const unsigned short* gB[3];
  unsigned short* lA[2];
  unsigned short* lB[3];
#pragma unroll
  for (int i = 0; i < 2; ++i) {
    const int c = i * 256 + tid;
    const int r = c >> 2;
    const int gc = (c & 3) ^ ((r >> 1) & 3);
    gA[i] = Abase + (size_t)r * K + gc * 8;
    lA[i] = (unsigned short*)As + (i * 256 + wave * 64) * 8;
  }
#pragma unroll
  for (int i = 0; i < 3; ++i) {
    const int c = i * 256 + tid;
    const int r = c >> 2;
    const int gc = (c & 3) ^ ((r >> 1) & 3);
    gB[i] = Bbase + (size_t)r * K + gc * 8;
    lB[i] = (unsigned short*)Bs + (i * 256 + wave * 64) * 8;
  }
  const int abufoff = 128 * 32;
  const int bbufoff = 192 * 32;

  const int fr = lane & 15;
  const int hi = lane >> 4;
  int afo[4], bfo[6];
#pragma unroll
  for (int m = 0; m < 4; ++m) {
    const int row = wr * 64 + m * 16 + fr;
    afo[m] = row * 32 + ((hi ^ ((row >> 1) & 3)) * 8);
  }
#pragma unroll
  for (int n = 0; n < 6; ++n) {
    const int row = wc * 96 + n * 16 + fr;
    bfo[n] = row * 32 + ((hi ^ ((row >> 1) & 3)) * 8);
  }

  f32x4 acc[4][6];
#pragma unroll
  for (int m = 0; m < 4; ++m)
#pragma unroll
    for (int n = 0; n < 6; ++n) {
      f32x4 z = {0.f, 0.f, 0.f, 0.f};
      acc[m][n] = z;
    }

  const int NT = K >> 5;

#pragma unroll
  for (int i = 0; i < 2; ++i) gload16(gA[i], lA[i]);
#pragma unroll
  for (int i = 0; i < 3; ++i) gload16(gB[i], lB[i]);
  __syncthreads();

  int cur = 0;
  for (int t = 0; t < NT; ++t) {
    if (t + 1 < NT) {
      const int nb = cur ^ 1;
      const int k0 = (t + 1) << 5;
#pragma unroll
      for (int i = 0; i < 2; ++i) gload16(gA[i] + k0, lA[i] + nb * abufoff);
#pragma unroll
      for (int i = 0; i < 3; ++i) gload16(gB[i] + k0, lB[i] + nb * bbufoff);
    }
    {
      const unsigned short* Ab = (const unsigned short*)As + cur * abufoff;
      const unsigned short* Bb = (const unsigned short*)Bs + cur * bbufoff;
      bf16x8 af[4], bfv[6];
#pragma unroll
      for (int m = 0; m < 4; ++m) af[m] = *(const bf16x8*)(Ab + afo[m]);
#pragma unroll
      for (int n = 0; n < 6; ++n) bfv[n] = *(const bf16x8*)(Bb + bfo[n]);
#pragma unroll
      for (int m = 0; m < 4; ++m)
#pragma unroll
        for (int n = 0; n < 6; ++n)
          acc[m][n] = __builtin_amdgcn_mfma_f32_16x16x32_bf16(af[m], bfv[n], acc[m][n], 0, 0, 0);
    }
    __syncthreads();
    cur ^= 1;
  }

  // epilogue -> head-major planes [col/48][row][48]
  const int rq = hi * 4;
#pragma unroll
  for (int m = 0; m < 4; ++m) {
#pragma unroll
    for (int n = 0; n < 6; ++n) {
      const int col = bn0 + wc * 96 + n * 16 + fr;
      const int pl = col / 48;
      const int d  = col - pl * 48;
      unsigned short* base = C + ((size_t)pl * M + bm0 + wr * 64 + m * 16 + rq) * 48 + d;
#pragma unroll
      for (int r = 0; r < 4; ++r)
        base[(size_t)r * 48] = f2bf(acc[m][n][r]);
    }
  }
}

// ---------------- FUSED windowed attention + proj GEMM ----------------
// Block = 128 tokens (4 y-strips x 32 x = 8 complete windows) x full 384 out-cols.
// Phase 1: attention (wave = window, loop 8 heads; r14 wave-code; O -> LDS attn tile).
// Phase 2: proj GEMM, A = attn tile in LDS (no staging), B = Wproj dbuf (r7 loop).
#define MTOK 131072
#define ASTR 392
__global__ __launch_bounds__(512, 2) void fused_attn_proj(const unsigned short* __restrict__ qkv,
                                                          const unsigned short* __restrict__ Wp,
                                                          const float* __restrict__ bias,
                                                          float* __restrict__ out) {
  __shared__ unsigned short lds[50176 + 24576];   // attn[128][392] | Bs dbuf / p1 scratch
  unsigned short* attn = lds;
  unsigned short* BsS  = lds + 50176;

  const int tid = threadIdx.x, lane = tid & 63, wave = tid >> 6;
  const int nwg = gridDim.x;                       // 1024, %8==0
  const int swz = (blockIdx.x & 7) * (nwg >> 3) + (blockIdx.x >> 3);
  const int b = swz >> 7, g2 = swz & 127;
  const int yb = g2 >> 2, xb = g2 & 3;
  const int imgbase = b * 16384;

  const int lg = lane >> 4;
  const int lr = lane & 15;

  // ===== phase 1: attention; per-wave scratch aliases the Bs region =====
  {
    unsigned short* Vt = BsS + wave * 1536;        // [48][24]
    unsigned short* P  = Vt + 48 * 24;             // [16][24]
    const int gtok = imgbase + (yb * 4 + (lr >> 2)) * 128 + xb * 32 + wave * 4 + (lr & 3);

    for (int h = 0; h < 8; ++h) {
      const size_t qb = ((size_t)h * MTOK + gtok) * 48;
      const size_t kb = ((size_t)(8 + h) * MTOK + gtok) * 48;
      const size_t vb = ((size_t)(16 + h) * MTOK + gtok) * 48;

      bf16x8 aq0 = *(const bf16x8*)(qkv + qb + lg * 8);
      bf16x8 bk0 = *(const bf16x8*)(qkv + kb + lg * 8);
      bf16x8 aq1 = {0, 0, 0, 0, 0, 0, 0, 0};
      bf16x8 bk1 = {0, 0, 0, 0, 0, 0, 0, 0};
      if (lg < 2) {
        aq1 = *(const bf16x8*)(qkv + qb + 32 + lg * 8);
        bk1 = *(const bf16x8*)(qkv + kb + 32 + lg * 8);
      }
      {
        bf16x8 v = *(const bf16x8*)(qkv + vb + lg * 8);
#pragma unroll
        for (int i = 0; i < 8; ++i) Vt[(lg * 8 + i) * 24 + lr] = (unsigned short)v[i];
        if (lane < 32) {
          bf16x8 v2 = *(const bf16x8*)(qkv + vb + 32 + lg * 8);
#pragma unroll
          for (int i = 0; i < 8; ++i) Vt[((4 + lg) * 8 + i) * 24 + lr] = (unsigned short)v2[i];
        }
      }

      f32x4 s = {0.f, 0.f, 0.f, 0.f};
      s = __builtin_amdgcn_mfma_f32_16x16x32_bf16(aq0, bk0, s, 0, 0, 0);
      s = __builtin_amdgcn_mfma_f32_16x16x32_bf16(aq1, bk1, s, 0, 0, 0);

      const float scale = 0.14433756729740643f;    // 1/sqrt(48)
      float p[4];
#pragma unroll
      for (int r = 0; r < 4; ++r) {
        float xv = s[r] * scale;
        float m = xv;
        m = fmaxf(m, __shfl_xor(m, 1));
        m = fmaxf(m, __shfl_xor(m, 2));
        m = fmaxf(m, __shfl_xor(m, 4));
        m = fmaxf(m, __shfl_xor(m, 8));
        float e = __expf(xv - m);
        float tt = e;
        tt += __shfl_xor(tt, 1);
        tt += __shfl_xor(tt, 2);
        tt += __shfl_xor(tt, 4);
        tt += __shfl_xor(tt, 8);
        p[r] = e / tt;
      }
#pragma unroll
      for (int r = 0; r < 4; ++r) P[(lg * 4 + r) * 24 + lr] = f2bf(p[r]);

      __syncthreads();                             // Vt/P writes ordered (all waves, aligned)

      bf16x8 ap = {0, 0, 0, 0, 0, 0, 0, 0};
      if (lg < 2) ap = *(const bf16x8*)(P + lr * 24 + lg * 8);

      f32x4 o[3];
#pragma unroll
      for (int c = 0; c < 3; ++c) {
        bf16x8 bv = {0, 0, 0, 0, 0, 0, 0, 0};
        if (lg < 2) bv = *(const bf16x8*)(Vt + (c * 16 + lr) * 24 + lg * 8);
        f32x4 z = {0.f, 0.f, 0.f, 0.f};
        o[c] = __builtin_amdgcn_mfma_f32_16x16x32_bf16(ap, bv, z, 0, 0, 0);
      }

      // O -> attn LDS tile: local token lq, col h*48 + c*16 + lr
#pragma unroll
      for (int r = 0; r < 4; ++r) {
        const int qi = lg * 4 + r;
        const int lq = (qi >> 2) * 32 + wave * 4 + (qi & 3);
#pragma unroll
        for (int c = 0; c < 3; ++c)
          attn[lq * ASTR + h * 48 + c * 16 + lr] = f2bf(o[c][r]);
      }
      __syncthreads();                             // Vt/P safe to overwrite next h
    }
  }
  // last in-loop barrier: all O writes visible, all scratch reads done -> Bs reusable

  // ===== phase 2: proj GEMM; A = attn tile (LDS-resident), B = Wp dbuf =====
  const int fr = lane & 15;
  const int hi = lane >> 4;
  const int wr = wave >> 1;        // 0..3 -> 32-row band
  const int wc = wave & 1;         // 0..1 -> 192-col band

  const unsigned short* gB[3];
  unsigned short* lB[3];
#pragma unroll
  for (int i = 0; i < 3; ++i) {
    const int c = i * 512 + tid;   // 1536 chunks: row 0..383, phys chunk 0..3
    const int r = c >> 2;
    const int gc = (c & 3) ^ ((r >> 1) & 3);
    gB[i] = Wp + (size_t)r * 384 + gc * 8;
    lB[i] = BsS + (i * 512 + wave * 64) * 8;
  }
  const int bbufoff = 384 * 32;    // shorts per B buffer

  int afo[2], bfo[12];
#pragma unroll
  for (int mf = 0; mf < 2; ++mf) {
    const int row = wr * 32 + mf * 16 + fr;
    afo[mf] = row * ASTR;          // + t*32 + hi*8 at read (pad-392 -> 2-way, free)
  }
#pragma unroll
  for (int nf = 0; nf < 12; ++nf) {
    const int row = wc * 192 + nf * 16 + fr;
    bfo[nf] = row * 32 + ((hi ^ ((row >> 1) & 3)) * 8);
  }

  f32x4 acc[2][12];
#pragma unroll
  for (int mf = 0; mf < 2; ++mf)
#pragma unroll
    for (int nf = 0; nf < 12; ++nf) {
      f32x4 z = {0.f, 0.f, 0.f, 0.f};
      acc[mf][nf] = z;
    }

  // prologue: stage B tile 0
#pragma unroll
  for (int i = 0; i < 3; ++i) gload16(gB[i], lB[i]);
  __syncthreads();

  int cur = 0;
  for (int t = 0; t < 12; ++t) {
    if (t + 1 < 12) {
      const int nb = cur ^ 1;
      const int k0 = (t + 1) << 5;
#pragma unroll
      for (int i = 0; i < 3; ++i) gload16(gB[i] + k0, lB[i] + nb * bbufoff);
    }
    {
      const unsigned short* Bb = BsS + cur * bbufoff;
      bf16x8 af[2], bfv[12];
#pragma unroll
      for (int mf = 0; mf < 2; ++mf)
        af[mf] = *(const bf16x8*)(attn + afo[mf] + t * 32 + hi * 8);
#pragma unroll
      for (int nf = 0; nf < 12; ++nf) bfv[nf] = *(const bf16x8*)(Bb + bfo[nf]);
#pragma unroll
      for (int mf = 0; mf < 2; ++mf)
#pragma unroll
        for (int nf = 0; nf < 12; ++nf)
          acc[mf][nf] = __builtin_amdgcn_mfma_f32_16x16x32_bf16(af[mf], bfv[nf], acc[mf][nf], 0, 0, 0);
    }
    __syncthreads();
    cur ^= 1;
  }

  // epilogue: fp32 out + bias; local row l -> strip-decoded global token
  const int rq = hi * 4;
#pragma unroll
  for (int mf = 0; mf < 2; ++mf) {
#pragma unroll
    for (int nf = 0; nf < 12; ++nf) {
      const int col = wc * 192 + nf * 16 + fr;
      const float bv = bias[col];
#pragma unroll
      for (int r = 0; r < 4; ++r) {
        const int l = wr * 32 + mf * 16 + rq + r;
        const int gtok = imgbase + (yb * 4 + (l >> 5)) * 128 + xb * 32 + (l & 31);
        out[(size_t)gtok * 384 + col] = acc[mf][nf][r] + bv;
      }
    }
  }
}

// ---------------- launch ----------------
extern "C" void kernel_launch(void* const* d_in, const int* in_sizes, int n_in,
                              void* d_out, int out_size, void* d_ws, size_t ws_size,
                              hipStream_t stream) {
  const float* x      = (const float*)d_in[0];
  const float* W_qkv  = (const float*)d_in[1];
  const float* W_proj = (const float*)d_in[2];
  const float* b_proj = (const float*)d_in[3];
  float* out = (float*)d_out;

  const int Bb = 8, Nn = 16384, Cc = 384;
  const int M = Bb * Nn;       // 131072
  const int threeC = 3 * Cc;   // 1152

  char* ws = (char*)d_ws;
  unsigned short* qkv_bf   = (unsigned short*)ws;                                  // 24 planes [M][48]
  unsigned short* x_bf     = (unsigned short*)(ws + (size_t)M * threeC * 2);       // M*384 bf16
  unsigned short* wqkv_bf  = (unsigned short*)(ws + (size_t)M * threeC * 2 + (size_t)M * Cc * 2);
  unsigned short* wproj_bf = wqkv_bf + threeC * Cc;

  conv_f32_bf16<<<2048, 256, 0, stream>>>((const float4*)x, (ushort4*)x_bf, M * Cc / 4);
  conv_f32_bf16<<<432, 256, 0, stream>>>((const float4*)W_qkv, (ushort4*)wqkv_bf, threeC * Cc / 4);
  conv_f32_bf16<<<144, 256, 0, stream>>>((const float4*)W_proj, (ushort4*)wproj_bf, Cc * Cc / 4);

  // qkv = x @ W_qkv^T (bf16, head-major planes): grid = 1024 x 6 = 6144 (%8==0)
  gemm_qkv<<<(M / 128) * (threeC / 192), 256, 0, stream>>>(x_bf, wqkv_bf, qkv_bf,
                                                           M, threeC, Cc);

  // fused attention + proj: 1024 strip-blocks (%8==0)
  fused_attn_proj<<<M / 128, 512, 0, stream>>>(qkv_bf, wproj_bf, b_proj, out);
}

// Round 16
// 398.710 us; speedup vs baseline: 1.0948x; 1.0212x over previous
//
#include <hip/hip_runtime.h>
#include <hip/hip_bf16.h>
#include <cstdint>

#define ASPACE(n) __attribute__((address_space(n)))

typedef short bf16x8 __attribute__((ext_vector_type(8)));
typedef float f32x4 __attribute__((ext_vector_type(4)));

__device__ __forceinline__ unsigned short f2bf(float f) {
  uint32_t u = __float_as_uint(f);
  u += 0x7fffu + ((u >> 16) & 1u);
  return (unsigned short)(u >> 16);
}
__device__ __forceinline__ float bf2f(unsigned short h) {
  return __uint_as_float(((uint32_t)h) << 16);
}

// ---------------- fp32 -> bf16 conversion ----------------
__global__ __launch_bounds__(256) void conv_f32_bf16(const float4* __restrict__ src,
                                                     ushort4* __restrict__ dst, int n4) {
  int i = blockIdx.x * blockDim.x + threadIdx.x;
  int stride = gridDim.x * blockDim.x;
  for (; i < n4; i += stride) {
    float4 v = src[i];
    ushort4 o;
    o.x = f2bf(v.x); o.y = f2bf(v.y); o.z = f2bf(v.z); o.w = f2bf(v.w);
    dst[i] = o;
  }
}

__device__ __forceinline__ void gload16(const unsigned short* g, unsigned short* l) {
  __builtin_amdgcn_global_load_lds((const ASPACE(1) void*)g, (ASPACE(3) void*)l, 16, 0, 0);
}

// ---------------- QKV GEMM (r7/r14-proven): bf16 out, HEAD-MAJOR planes ----------------
__global__ __launch_bounds__(256, 3) void gemm_qkv(const unsigned short* __restrict__ A,
                                                   const unsigned short* __restrict__ B,
                                                   unsigned short* __restrict__ C,
                                                   int M, int N, int K) {
  __shared__ unsigned short As[2][128 * 32];
  __shared__ unsigned short Bs[2][192 * 32];

  const int tid  = threadIdx.x;
  const int lane = tid & 63;
  const int wave = tid >> 6;
  const int wr = wave >> 1;
  const int wc = wave & 1;

  const int nwg = gridDim.x;
  const int swz = (blockIdx.x & 7) * (nwg >> 3) + (blockIdx.x >> 3);
  const int ntn = N / 192;
  const int bn0 = (swz % ntn) * 192;
  const int bm0 = (swz / ntn) << 7;

  const unsigned short* Abase = A + (size_t)bm0 * K;
  const unsigned short* Bbase = B + (size_t)bn0 * K;

  const unsigned short* gA[2];
  const unsigned short* gB[3];
  unsigned short* lA[2];
  unsigned short* lB[3];
#pragma unroll
  for (int i = 0; i < 2; ++i) {
    const int c = i * 256 + tid;
    const int r = c >> 2;
    const int gc = (c & 3) ^ ((r >> 1) & 3);
    gA[i] = Abase + (size_t)r * K + gc * 8;
    lA[i] = (unsigned short*)As + (i * 256 + wave * 64) * 8;
  }
#pragma unroll
  for (int i = 0; i < 3; ++i) {
    const int c = i * 256 + tid;
    const int r = c >> 2;
    const int gc = (c & 3) ^ ((r >> 1) & 3);
    gB[i] = Bbase + (size_t)r * K + gc * 8;
    lB[i] = (unsigned short*)Bs + (i * 256 + wave * 64) * 8;
  }
  const int abufoff = 128 * 32;
  const int bbufoff = 192 * 32;

  const int fr = lane & 15;
  const int hi = lane >> 4;
  int afo[4], bfo[6];
#pragma unroll
  for (int m = 0; m < 4; ++m) {
    const int row = wr * 64 + m * 16 + fr;
    afo[m] = row * 32 + ((hi ^ ((row >> 1) & 3)) * 8);
  }
#pragma unroll
  for (int n = 0; n < 6; ++n) {
    const int row = wc * 96 + n * 16 + fr;
    bfo[n] = row * 32 + ((hi ^ ((row >> 1) & 3)) * 8);
  }

  f32x4 acc[4][6];
#pragma unroll
  for (int m = 0; m < 4; ++m)
#pragma unroll
    for (int n = 0; n < 6; ++n) {
      f32x4 z = {0.f, 0.f, 0.f, 0.f};
      acc[m][n] = z;
    }

  const int NT = K >> 5;

#pragma unroll
  for (int i = 0; i < 2; ++i) gload16(gA[i], lA[i]);
#pragma unroll
  for (int i = 0; i < 3; ++i) gload16(gB[i], lB[i]);
  __syncthreads();

  int cur = 0;
  for (int t = 0; t < NT; ++t) {
    if (t + 1 < NT) {
      const int nb = cur ^ 1;
      const int k0 = (t + 1) << 5;
#pragma unroll
      for (int i = 0; i < 2; ++i) gload16(gA[i] + k0, lA[i] + nb * abufoff);
#pragma unroll
      for (int i = 0; i < 3; ++i) gload16(gB[i] + k0, lB[i] + nb * bbufoff);
    }
    {
      const unsigned short* Ab = (const unsigned short*)As + cur * abufoff;
      const unsigned short* Bb = (const unsigned short*)Bs + cur * bbufoff;
      bf16x8 af[4], bfv[6];
#pragma unroll
      for (int m = 0; m < 4; ++m) af[m] = *(const bf16x8*)(Ab + afo[m]);
#pragma unroll
      for (int n = 0; n < 6; ++n) bfv[n] = *(const bf16x8*)(Bb + bfo[n]);
#pragma unroll
      for (int m = 0; m < 4; ++m)
#pragma unroll
        for (int n = 0; n < 6; ++n)
          acc[m][n] = __builtin_amdgcn_mfma_f32_16x16x32_bf16(af[m], bfv[n], acc[m][n], 0, 0, 0);
    }
    __syncthreads();
    cur ^= 1;
  }

  // epilogue -> head-major planes [col/48][row][48]
  const int rq = hi * 4;
#pragma unroll
  for (int m = 0; m < 4; ++m) {
#pragma unroll
    for (int n = 0; n < 6; ++n) {
      const int col = bn0 + wc * 96 + n * 16 + fr;
      const int pl = col / 48;
      const int d  = col - pl * 48;
      unsigned short* base = C + ((size_t)pl * M + bm0 + wr * 64 + m * 16 + rq) * 48 + d;
#pragma unroll
      for (int r = 0; r < 4; ++r)
        base[(size_t)r * 48] = f2bf(acc[m][n][r]);
    }
  }
}

// ---------------- FUSED windowed attention + proj GEMM ----------------
// Block = 128 tokens (4 y-strips x 32 x = 8 complete windows) x full 384 out-cols.
// Phase 1: attention, wave = window, loop 8 heads -- NO in-loop barriers: Vt/P scratch
// is per-wave private (disjoint BsS ranges) and same-wave LDS write->read ordering is
// guaranteed by the in-order DS pipeline + compiler lgkm waits. ONE barrier after the
// h-loop publishes attn[] and frees BsS for phase 2.
// Phase 2: proj GEMM, A = attn tile in LDS (no staging), B = Wproj dbuf (r7 loop).
#define MTOK 131072
#define ASTR 392
__global__ __launch_bounds__(512, 2) void fused_attn_proj(const unsigned short* __restrict__ qkv,
                                                          const unsigned short* __restrict__ Wp,
                                                          const float* __restrict__ bias,
                                                          float* __restrict__ out) {
  __shared__ unsigned short lds[50176 + 24576];   // attn[128][392] | Bs dbuf / p1 scratch
  unsigned short* attn = lds;
  unsigned short* BsS  = lds + 50176;

  const int tid = threadIdx.x, lane = tid & 63, wave = tid >> 6;
  const int nwg = gridDim.x;                       // 1024, %8==0
  const int swz = (blockIdx.x & 7) * (nwg >> 3) + (blockIdx.x >> 3);
  const int b = swz >> 7, g2 = swz & 127;
  const int yb = g2 >> 2, xb = g2 & 3;
  const int imgbase = b * 16384;

  const int lg = lane >> 4;
  const int lr = lane & 15;

  // ===== phase 1: attention; per-wave scratch aliases the Bs region =====
  {
    unsigned short* Vt = BsS + wave * 1536;        // [48][24]
    unsigned short* P  = Vt + 48 * 24;             // [16][24]
    const int gtok = imgbase + (yb * 4 + (lr >> 2)) * 128 + xb * 32 + wave * 4 + (lr & 3);

    for (int h = 0; h < 8; ++h) {
      const size_t qb = ((size_t)h * MTOK + gtok) * 48;
      const size_t kb = ((size_t)(8 + h) * MTOK + gtok) * 48;
      const size_t vb = ((size_t)(16 + h) * MTOK + gtok) * 48;

      bf16x8 aq0 = *(const bf16x8*)(qkv + qb + lg * 8);
      bf16x8 bk0 = *(const bf16x8*)(qkv + kb + lg * 8);
      bf16x8 aq1 = {0, 0, 0, 0, 0, 0, 0, 0};
      bf16x8 bk1 = {0, 0, 0, 0, 0, 0, 0, 0};
      if (lg < 2) {
        aq1 = *(const bf16x8*)(qkv + qb + 32 + lg * 8);
        bk1 = *(const bf16x8*)(qkv + kb + 32 + lg * 8);
      }
      {
        bf16x8 v = *(const bf16x8*)(qkv + vb + lg * 8);
#pragma unroll
        for (int i = 0; i < 8; ++i) Vt[(lg * 8 + i) * 24 + lr] = (unsigned short)v[i];
        if (lane < 32) {
          bf16x8 v2 = *(const bf16x8*)(qkv + vb + 32 + lg * 8);
#pragma unroll
          for (int i = 0; i < 8; ++i) Vt[((4 + lg) * 8 + i) * 24 + lr] = (unsigned short)v2[i];
        }
      }

      f32x4 s = {0.f, 0.f, 0.f, 0.f};
      s = __builtin_amdgcn_mfma_f32_16x16x32_bf16(aq0, bk0, s, 0, 0, 0);
      s = __builtin_amdgcn_mfma_f32_16x16x32_bf16(aq1, bk1, s, 0, 0, 0);

      const float scale = 0.14433756729740643f;    // 1/sqrt(48)
      float p[4];
#pragma unroll
      for (int r = 0; r < 4; ++r) {
        float xv = s[r] * scale;
        float m = xv;
        m = fmaxf(m, __shfl_xor(m, 1));
        m = fmaxf(m, __shfl_xor(m, 2));
        m = fmaxf(m, __shfl_xor(m, 4));
        m = fmaxf(m, __shfl_xor(m, 8));
        float e = __expf(xv - m);
        float tt = e;
        tt += __shfl_xor(tt, 1);
        tt += __shfl_xor(tt, 2);
        tt += __shfl_xor(tt, 4);
        tt += __shfl_xor(tt, 8);
        p[r] = e / tt;
      }
#pragma unroll
      for (int r = 0; r < 4; ++r) P[(lg * 4 + r) * 24 + lr] = f2bf(p[r]);
      // no barrier: same-wave DS ordering (in-order DS pipe + compiler lgkm waits)

      bf16x8 ap = {0, 0, 0, 0, 0, 0, 0, 0};
      if (lg < 2) ap = *(const bf16x8*)(P + lr * 24 + lg * 8);

      f32x4 o[3];
#pragma unroll
      for (int c = 0; c < 3; ++c) {
        bf16x8 bv = {0, 0, 0, 0, 0, 0, 0, 0};
        if (lg < 2) bv = *(const bf16x8*)(Vt + (c * 16 + lr) * 24 + lg * 8);
        f32x4 z = {0.f, 0.f, 0.f, 0.f};
        o[c] = __builtin_amdgcn_mfma_f32_16x16x32_bf16(ap, bv, z, 0, 0, 0);
      }

      // O -> attn LDS tile: local token lq, col h*48 + c*16 + lr
#pragma unroll
      for (int r = 0; r < 4; ++r) {
        const int qi = lg * 4 + r;
        const int lq = (qi >> 2) * 32 + wave * 4 + (qi & 3);
#pragma unroll
        for (int c = 0; c < 3; ++c)
          attn[lq * ASTR + h * 48 + c * 16 + lr] = f2bf(o[c][r]);
      }
      // no barrier: next h only touches this wave's own Vt/P (private)
    }
  }
  __syncthreads();   // attn[] published to all waves; all scratch reads done -> BsS free

  // ===== phase 2: proj GEMM; A = attn tile (LDS-resident), B = Wp dbuf =====
  const int fr = lane & 15;
  const int hi = lane >> 4;
  const int wr = wave >> 1;        // 0..3 -> 32-row band
  const int wc = wave & 1;         // 0..1 -> 192-col band

  const unsigned short* gB[3];
  unsigned short* lB[3];
#pragma unroll
  for (int i = 0; i < 3; ++i) {
    const int c = i * 512 + tid;   // 1536 chunks: row 0..383, phys chunk 0..3
    const int r = c >> 2;
    const int gc = (c & 3) ^ ((r >> 1) & 3);
    gB[i] = Wp + (size_t)r * 384 + gc * 8;
    lB[i] = BsS + (i * 512 + wave * 64) * 8;
  }
  const int bbufoff = 384 * 32;    // shorts per B buffer

  int afo[2], bfo[12];
#pragma unroll
  for (int mf = 0; mf < 2; ++mf) {
    const int row = wr * 32 + mf * 16 + fr;
    afo[mf] = row * ASTR;          // + t*32 + hi*8 at read (pad-392 -> 2-way, free)
  }
#pragma unroll
  for (int nf = 0; nf < 12; ++nf) {
    const int row = wc * 192 + nf * 16 + fr;
    bfo[nf] = row * 32 + ((hi ^ ((row >> 1) & 3)) * 8);
  }

  f32x4 acc[2][12];
#pragma unroll
  for (int mf = 0; mf < 2; ++mf)
#pragma unroll
    for (int nf = 0; nf < 12; ++nf) {
      f32x4 z = {0.f, 0.f, 0.f, 0.f};
      acc[mf][nf] = z;
    }

  // prologue: stage B tile 0
#pragma unroll
  for (int i = 0; i < 3; ++i) gload16(gB[i], lB[i]);
  __syncthreads();

  int cur = 0;
  for (int t = 0; t < 12; ++t) {
    if (t + 1 < 12) {
      const int nb = cur ^ 1;
      const int k0 = (t + 1) << 5;
#pragma unroll
      for (int i = 0; i < 3; ++i) gload16(gB[i] + k0, lB[i] + nb * bbufoff);
    }
    {
      const unsigned short* Bb = BsS + cur * bbufoff;
      bf16x8 af[2], bfv[12];
#pragma unroll
      for (int mf = 0; mf < 2; ++mf)
        af[mf] = *(const bf16x8*)(attn + afo[mf] + t * 32 + hi * 8);
#pragma unroll
      for (int nf = 0; nf < 12; ++nf) bfv[nf] = *(const bf16x8*)(Bb + bfo[nf]);
#pragma unroll
      for (int mf = 0; mf < 2; ++mf)
#pragma unroll
        for (int nf = 0; nf < 12; ++nf)
          acc[mf][nf] = __builtin_amdgcn_mfma_f32_16x16x32_bf16(af[mf], bfv[nf], acc[mf][nf], 0, 0, 0);
    }
    __syncthreads();
    cur ^= 1;
  }

  // epilogue: fp32 out + bias; local row l -> strip-decoded global token
  const int rq = hi * 4;
#pragma unroll
  for (int mf = 0; mf < 2; ++mf) {
#pragma unroll
    for (int nf = 0; nf < 12; ++nf) {
      const int col = wc * 192 + nf * 16 + fr;
      const float bv = bias[col];
#pragma unroll
      for (int r = 0; r < 4; ++r) {
        const int l = wr * 32 + mf * 16 + rq + r;
        const int gtok = imgbase + (yb * 4 + (l >> 5)) * 128 + xb * 32 + (l & 31);
        out[(size_t)gtok * 384 + col] = acc[mf][nf][r] + bv;
      }
    }
  }
}

// ---------------- launch ----------------
extern "C" void kernel_launch(void* const* d_in, const int* in_sizes, int n_in,
                              void* d_out, int out_size, void* d_ws, size_t ws_size,
                              hipStream_t stream) {
  const float* x      = (const float*)d_in[0];
  const float* W_qkv  = (const float*)d_in[1];
  const float* W_proj = (const float*)d_in[2];
  const float* b_proj = (const float*)d_in[3];
  float* out = (float*)d_out;

  const int Bb = 8, Nn = 16384, Cc = 384;
  const int M = Bb * Nn;       // 131072
  const int threeC = 3 * Cc;   // 1152

  char* ws = (char*)d_ws;
  unsigned short* qkv_bf   = (unsigned short*)ws;                                  // 24 planes [M][48]
  unsigned short* x_bf     = (unsigned short*)(ws + (size_t)M * threeC * 2);       // M*384 bf16
  unsigned short* wqkv_bf  = (unsigned short*)(ws + (size_t)M * threeC * 2 + (size_t)M * Cc * 2);
  unsigned short* wproj_bf = wqkv_bf + threeC * Cc;

  conv_f32_bf16<<<2048, 256, 0, stream>>>((const float4*)x, (ushort4*)x_bf, M * Cc / 4);
  conv_f32_bf16<<<432, 256, 0, stream>>>((const float4*)W_qkv, (ushort4*)wqkv_bf, threeC * Cc / 4);
  conv_f32_bf16<<<144, 256, 0, stream>>>((const float4*)W_proj, (ushort4*)wproj_bf, Cc * Cc / 4);

  // qkv = x @ W_qkv^T (bf16, head-major planes): grid = 1024 x 6 = 6144 (%8==0)
  gemm_qkv<<<(M / 128) * (threeC / 192), 256, 0, stream>>>(x_bf, wqkv_bf, qkv_bf,
                                                           M, threeC, Cc);

  // fused attention + proj: 1024 strip-blocks (%8==0)
  fused_attn_proj<<<M / 128, 512, 0, stream>>>(qkv_bf, wproj_bf, b_proj, out);
}

// Round 17
// 387.078 us; speedup vs baseline: 1.1277x; 1.0301x over previous
//
#include <hip/hip_runtime.h>
#include <hip/hip_bf16.h>
#include <cstdint>

#define ASPACE(n) __attribute__((address_space(n)))

typedef short bf16x8 __attribute__((ext_vector_type(8)));
typedef float f32x4 __attribute__((ext_vector_type(4)));

__device__ __forceinline__ unsigned short f2bf(float f) {
  uint32_t u = __float_as_uint(f);
  u += 0x7fffu + ((u >> 16) & 1u);
  return (unsigned short)(u >> 16);
}
__device__ __forceinline__ float bf2f(unsigned short h) {
  return __uint_as_float(((uint32_t)h) << 16);
}

// pack 8 fp32 -> bf16x8 via v_cvt_pk_bf16_f32 (RNE, matches f2bf)
__device__ __forceinline__ bf16x8 cvt8(float4 a, float4 b) {
  union { uint32_t u[4]; bf16x8 v; } r;
  asm("v_cvt_pk_bf16_f32 %0, %1, %2" : "=v"(r.u[0]) : "v"(a.x), "v"(a.y));
  asm("v_cvt_pk_bf16_f32 %0, %1, %2" : "=v"(r.u[1]) : "v"(a.z), "v"(a.w));
  asm("v_cvt_pk_bf16_f32 %0, %1, %2" : "=v"(r.u[2]) : "v"(b.x), "v"(b.y));
  asm("v_cvt_pk_bf16_f32 %0, %1, %2" : "=v"(r.u[3]) : "v"(b.z), "v"(b.w));
  return r.v;
}

// ---------------- fp32 -> bf16 conversion (weights only) ----------------
__global__ __launch_bounds__(256) void conv_f32_bf16(const float4* __restrict__ src,
                                                     ushort4* __restrict__ dst, int n4) {
  int i = blockIdx.x * blockDim.x + threadIdx.x;
  int stride = gridDim.x * blockDim.x;
  for (; i < n4; i += stride) {
    float4 v = src[i];
    ushort4 o;
    o.x = f2bf(v.x); o.y = f2bf(v.y); o.z = f2bf(v.z); o.w = f2bf(v.w);
    dst[i] = o;
  }
}

__device__ __forceinline__ void gload16(const unsigned short* g, unsigned short* l) {
  __builtin_amdgcn_global_load_lds((const ASPACE(1) void*)g, (ASPACE(3) void*)l, 16, 0, 0);
}

// ---------------- QKV GEMM reading fp32 x directly (conv-x pass eliminated) ----------------
// C[m,n] = sum_k bf16(x[m,k]) * B[n,k]; BM=128, BN=192, BK=32; r7-proven 2-phase loop.
// A: REGISTER-staged (fp32 float4 pairs -> cvt_pk -> bf16 ds_write_b128) into the SAME
// bf16 LDS layout/swizzle as r7 (40 KB total, 3 blocks/CU preserved; frag reads identical).
// B: gload16 DMA staging (r7-verbatim). Loads issued before compute, cvt+write after.
__global__ __launch_bounds__(256, 3) void gemm_qkv(const float* __restrict__ x,
                                                   const unsigned short* __restrict__ B,
                                                   unsigned short* __restrict__ C,
                                                   int M, int N, int K) {
  __shared__ unsigned short As[2][128 * 32];   // 16 KiB (bf16)
  __shared__ unsigned short Bs[2][192 * 32];   // 24 KiB

  const int tid  = threadIdx.x;
  const int lane = tid & 63;
  const int wave = tid >> 6;
  const int wr = wave >> 1;
  const int wc = wave & 1;

  const int nwg = gridDim.x;
  const int swz = (blockIdx.x & 7) * (nwg >> 3) + (blockIdx.x >> 3);
  const int ntn = N / 192;
  const int bn0 = (swz % ntn) * 192;
  const int bm0 = (swz / ntn) << 7;

  const unsigned short* Bbase = B + (size_t)bn0 * K;

  // A staging: 512 chunks (128 rows x 4 bf16-chunks); 2 per thread; swizzle (row>>1)&3.
  // Global source fp32; LDS dest linear at chunk c (short offset c*8).
  const float* gAf[2];
  int wAo[2];
#pragma unroll
  for (int i = 0; i < 2; ++i) {
    const int c = i * 256 + tid;
    const int r = c >> 2;
    const int gc = (c & 3) ^ ((r >> 1) & 3);
    gAf[i] = x + (size_t)(bm0 + r) * K + gc * 8;
    wAo[i] = c * 8;
  }
  // B staging (r7-verbatim)
  const unsigned short* gB[3];
  unsigned short* lB[3];
#pragma unroll
  for (int i = 0; i < 3; ++i) {
    const int c = i * 256 + tid;
    const int r = c >> 2;
    const int gc = (c & 3) ^ ((r >> 1) & 3);
    gB[i] = Bbase + (size_t)r * K + gc * 8;
    lB[i] = (unsigned short*)Bs + (i * 256 + wave * 64) * 8;
  }
  const int abufoff = 128 * 32;
  const int bbufoff = 192 * 32;

  const int fr = lane & 15;
  const int hi = lane >> 4;
  int afo[4], bfo[6];
#pragma unroll
  for (int m = 0; m < 4; ++m) {
    const int row = wr * 64 + m * 16 + fr;
    afo[m] = row * 32 + ((hi ^ ((row >> 1) & 3)) * 8);
  }
#pragma unroll
  for (int n = 0; n < 6; ++n) {
    const int row = wc * 96 + n * 16 + fr;
    bfo[n] = row * 32 + ((hi ^ ((row >> 1) & 3)) * 8);
  }

  f32x4 acc[4][6];
#pragma unroll
  for (int m = 0; m < 4; ++m)
#pragma unroll
    for (int n = 0; n < 6; ++n) {
      f32x4 z = {0.f, 0.f, 0.f, 0.f};
      acc[m][n] = z;
    }

  const int NT = K >> 5;          // 12

  // prologue: tile 0
  float4 a0[2], a1[2];
#pragma unroll
  for (int i = 0; i < 2; ++i) { a0[i] = *(const float4*)(gAf[i]); a1[i] = *(const float4*)(gAf[i] + 4); }
#pragma unroll
  for (int i = 0; i < 3; ++i) gload16(gB[i], lB[i]);
#pragma unroll
  for (int i = 0; i < 2; ++i)
    *(bf16x8*)((unsigned short*)As + wAo[i]) = cvt8(a0[i], a1[i]);
  __syncthreads();

  int cur = 0;
  for (int t = 0; t < NT; ++t) {
    const int nb = cur ^ 1;
    if (t + 1 < NT) {            // issue next-tile loads first (land under compute)
      const int k0 = (t + 1) << 5;
#pragma unroll
      for (int i = 0; i < 2; ++i) { a0[i] = *(const float4*)(gAf[i] + k0); a1[i] = *(const float4*)(gAf[i] + k0 + 4); }
#pragma unroll
      for (int i = 0; i < 3; ++i) gload16(gB[i] + k0, lB[i] + nb * bbufoff);
    }
    // compute tile t
    {
      const unsigned short* Ab = (const unsigned short*)As + cur * abufoff;
      const unsigned short* Bb = (const unsigned short*)Bs + cur * bbufoff;
      bf16x8 af[4], bfv[6];
#pragma unroll
      for (int m = 0; m < 4; ++m) af[m] = *(const bf16x8*)(Ab + afo[m]);
#pragma unroll
      for (int n = 0; n < 6; ++n) bfv[n] = *(const bf16x8*)(Bb + bfo[n]);
#pragma unroll
      for (int m = 0; m < 4; ++m)
#pragma unroll
        for (int n = 0; n < 6; ++n)
          acc[m][n] = __builtin_amdgcn_mfma_f32_16x16x32_bf16(af[m], bfv[n], acc[m][n], 0, 0, 0);
    }
    if (t + 1 < NT) {            // A(t+1): cvt in-reg, ds_write into buf nb
#pragma unroll
      for (int i = 0; i < 2; ++i)
        *(bf16x8*)((unsigned short*)As + nb * abufoff + wAo[i]) = cvt8(a0[i], a1[i]);
    }
    __syncthreads();             // drains B DMA + A ds_writes; buf nb complete
    cur ^= 1;
  }

  // epilogue -> head-major planes [col/48][row][48]
  const int rq = hi * 4;
#pragma unroll
  for (int m = 0; m < 4; ++m) {
#pragma unroll
    for (int n = 0; n < 6; ++n) {
      const int col = bn0 + wc * 96 + n * 16 + fr;
      const int pl = col / 48;
      const int d  = col - pl * 48;
      unsigned short* base = C + ((size_t)pl * M + bm0 + wr * 64 + m * 16 + rq) * 48 + d;
#pragma unroll
      for (int r = 0; r < 4; ++r)
        base[(size_t)r * 48] = f2bf(acc[m][n][r]);
    }
  }
}

// ---------------- FUSED windowed attention + proj GEMM (r16-verbatim) ----------------
#define MTOK 131072
#define ASTR 392
__global__ __launch_bounds__(512, 2) void fused_attn_proj(const unsigned short* __restrict__ qkv,
                                                          const unsigned short* __restrict__ Wp,
                                                          const float* __restrict__ bias,
                                                          float* __restrict__ out) {
  __shared__ unsigned short lds[50176 + 24576];   // attn[128][392] | Bs dbuf / p1 scratch
  unsigned short* attn = lds;
  unsigned short* BsS  = lds + 50176;

  const int tid = threadIdx.x, lane = tid & 63, wave = tid >> 6;
  const int nwg = gridDim.x;                       // 1024, %8==0
  const int swz = (blockIdx.x & 7) * (nwg >> 3) + (blockIdx.x >> 3);
  const int b = swz >> 7, g2 = swz & 127;
  const int yb = g2 >> 2, xb = g2 & 3;
  const int imgbase = b * 16384;

  const int lg = lane >> 4;
  const int lr = lane & 15;

  // ===== phase 1: attention; per-wave private scratch; no in-loop barriers =====
  {
    unsigned short* Vt = BsS + wave * 1536;        // [48][24]
    unsigned short* P  = Vt + 48 * 24;             // [16][24]
    const int gtok = imgbase + (yb * 4 + (lr >> 2)) * 128 + xb * 32 + wave * 4 + (lr & 3);

    for (int h = 0; h < 8; ++h) {
      const size_t qb = ((size_t)h * MTOK + gtok) * 48;
      const size_t kb = ((size_t)(8 + h) * MTOK + gtok) * 48;
      const size_t vb = ((size_t)(16 + h) * MTOK + gtok) * 48;

      bf16x8 aq0 = *(const bf16x8*)(qkv + qb + lg * 8);
      bf16x8 bk0 = *(const bf16x8*)(qkv + kb + lg * 8);
      bf16x8 aq1 = {0, 0, 0, 0, 0, 0, 0, 0};
      bf16x8 bk1 = {0, 0, 0, 0, 0, 0, 0, 0};
      if (lg < 2) {
        aq1 = *(const bf16x8*)(qkv + qb + 32 + lg * 8);
        bk1 = *(const bf16x8*)(qkv + kb + 32 + lg * 8);
      }
      {
        bf16x8 v = *(const bf16x8*)(qkv + vb + lg * 8);
#pragma unroll
        for (int i = 0; i < 8; ++i) Vt[(lg * 8 + i) * 24 + lr] = (unsigned short)v[i];
        if (lane < 32) {
          bf16x8 v2 = *(const bf16x8*)(qkv + vb + 32 + lg * 8);
#pragma unroll
          for (int i = 0; i < 8; ++i) Vt[((4 + lg) * 8 + i) * 24 + lr] = (unsigned short)v2[i];
        }
      }

      f32x4 s = {0.f, 0.f, 0.f, 0.f};
      s = __builtin_amdgcn_mfma_f32_16x16x32_bf16(aq0, bk0, s, 0, 0, 0);
      s = __builtin_amdgcn_mfma_f32_16x16x32_bf16(aq1, bk1, s, 0, 0, 0);

      const float scale = 0.14433756729740643f;    // 1/sqrt(48)
      float p[4];
#pragma unroll
      for (int r = 0; r < 4; ++r) {
        float xv = s[r] * scale;
        float m = xv;
        m = fmaxf(m, __shfl_xor(m, 1));
        m = fmaxf(m, __shfl_xor(m, 2));
        m = fmaxf(m, __shfl_xor(m, 4));
        m = fmaxf(m, __shfl_xor(m, 8));
        float e = __expf(xv - m);
        float tt = e;
        tt += __shfl_xor(tt, 1);
        tt += __shfl_xor(tt, 2);
        tt += __shfl_xor(tt, 4);
        tt += __shfl_xor(tt, 8);
        p[r] = e / tt;
      }
#pragma unroll
      for (int r = 0; r < 4; ++r) P[(lg * 4 + r) * 24 + lr] = f2bf(p[r]);

      bf16x8 ap = {0, 0, 0, 0, 0, 0, 0, 0};
      if (lg < 2) ap = *(const bf16x8*)(P + lr * 24 + lg * 8);

      f32x4 o[3];
#pragma unroll
      for (int c = 0; c < 3; ++c) {
        bf16x8 bv = {0, 0, 0, 0, 0, 0, 0, 0};
        if (lg < 2) bv = *(const bf16x8*)(Vt + (c * 16 + lr) * 24 + lg * 8);
        f32x4 z = {0.f, 0.f, 0.f, 0.f};
        o[c] = __builtin_amdgcn_mfma_f32_16x16x32_bf16(ap, bv, z, 0, 0, 0);
      }

#pragma unroll
      for (int r = 0; r < 4; ++r) {
        const int qi = lg * 4 + r;
        const int lq = (qi >> 2) * 32 + wave * 4 + (qi & 3);
#pragma unroll
        for (int c = 0; c < 3; ++c)
          attn[lq * ASTR + h * 48 + c * 16 + lr] = f2bf(o[c][r]);
      }
    }
  }
  __syncthreads();   // attn[] published; scratch reads done -> BsS free

  // ===== phase 2: proj GEMM; A = attn tile (LDS-resident), B = Wp dbuf =====
  const int fr = lane & 15;
  const int hi = lane >> 4;
  const int wr = wave >> 1;
  const int wc = wave & 1;

  const unsigned short* gB[3];
  unsigned short* lB[3];
#pragma unroll
  for (int i = 0; i < 3; ++i) {
    const int c = i * 512 + tid;
    const int r = c >> 2;
    const int gc = (c & 3) ^ ((r >> 1) & 3);
    gB[i] = Wp + (size_t)r * 384 + gc * 8;
    lB[i] = BsS + (i * 512 + wave * 64) * 8;
  }
  const int bbufoff = 384 * 32;

  int afo[2], bfo[12];
#pragma unroll
  for (int mf = 0; mf < 2; ++mf) {
    const int row = wr * 32 + mf * 16 + fr;
    afo[mf] = row * ASTR;
  }
#pragma unroll
  for (int nf = 0; nf < 12; ++nf) {
    const int row = wc * 192 + nf * 16 + fr;
    bfo[nf] = row * 32 + ((hi ^ ((row >> 1) & 3)) * 8);
  }

  f32x4 acc[2][12];
#pragma unroll
  for (int mf = 0; mf < 2; ++mf)
#pragma unroll
    for (int nf = 0; nf < 12; ++nf) {
      f32x4 z = {0.f, 0.f, 0.f, 0.f};
      acc[mf][nf] = z;
    }

#pragma unroll
  for (int i = 0; i < 3; ++i) gload16(gB[i], lB[i]);
  __syncthreads();

  int cur = 0;
  for (int t = 0; t < 12; ++t) {
    if (t + 1 < 12) {
      const int nb = cur ^ 1;
      const int k0 = (t + 1) << 5;
#pragma unroll
      for (int i = 0; i < 3; ++i) gload16(gB[i] + k0, lB[i] + nb * bbufoff);
    }
    {
      const unsigned short* Bb = BsS + cur * bbufoff;
      bf16x8 af[2], bfv[12];
#pragma unroll
      for (int mf = 0; mf < 2; ++mf)
        af[mf] = *(const bf16x8*)(attn + afo[mf] + t * 32 + hi * 8);
#pragma unroll
      for (int nf = 0; nf < 12; ++nf) bfv[nf] = *(const bf16x8*)(Bb + bfo[nf]);
#pragma unroll
      for (int mf = 0; mf < 2; ++mf)
#pragma unroll
        for (int nf = 0; nf < 12; ++nf)
          acc[mf][nf] = __builtin_amdgcn_mfma_f32_16x16x32_bf16(af[mf], bfv[nf], acc[mf][nf], 0, 0, 0);
    }
    __syncthreads();
    cur ^= 1;
  }

  const int rq = hi * 4;
#pragma unroll
  for (int mf = 0; mf < 2; ++mf) {
#pragma unroll
    for (int nf = 0; nf < 12; ++nf) {
      const int col = wc * 192 + nf * 16 + fr;
      const float bv = bias[col];
#pragma unroll
      for (int r = 0; r < 4; ++r) {
        const int l = wr * 32 + mf * 16 + rq + r;
        const int gtok = imgbase + (yb * 4 + (l >> 5)) * 128 + xb * 32 + (l & 31);
        out[(size_t)gtok * 384 + col] = acc[mf][nf][r] + bv;
      }
    }
  }
}

// ---------------- launch ----------------
extern "C" void kernel_launch(void* const* d_in, const int* in_sizes, int n_in,
                              void* d_out, int out_size, void* d_ws, size_t ws_size,
                              hipStream_t stream) {
  const float* x      = (const float*)d_in[0];
  const float* W_qkv  = (const float*)d_in[1];
  const float* W_proj = (const float*)d_in[2];
  const float* b_proj = (const float*)d_in[3];
  float* out = (float*)d_out;

  const int Bb = 8, Nn = 16384, Cc = 384;
  const int M = Bb * Nn;       // 131072
  const int threeC = 3 * Cc;   // 1152

  char* ws = (char*)d_ws;
  unsigned short* qkv_bf   = (unsigned short*)ws;                         // 24 planes [M][48]
  unsigned short* wqkv_bf  = (unsigned short*)(ws + (size_t)M * threeC * 2);
  unsigned short* wproj_bf = wqkv_bf + threeC * Cc;

  // weight conversions only (tiny)
  conv_f32_bf16<<<432, 256, 0, stream>>>((const float4*)W_qkv, (ushort4*)wqkv_bf,
                                         threeC * Cc / 4);
  conv_f32_bf16<<<144, 256, 0, stream>>>((const float4*)W_proj, (ushort4*)wproj_bf,
                                         Cc * Cc / 4);

  // qkv = bf16(x) @ W_qkv^T (fp32 x read directly; head-major planes): 1024 x 6 = 6144
  gemm_qkv<<<(M / 128) * (threeC / 192), 256, 0, stream>>>(x, wqkv_bf, qkv_bf,
                                                           M, threeC, Cc);

  // fused attention + proj: 1024 strip-blocks (%8==0)
  fused_attn_proj<<<M / 128, 512, 0, stream>>>(qkv_bf, wproj_bf, b_proj, out);
}